// Round 11
// baseline (199.703 us; speedup 1.0000x reference)
//
#include <hip/hip_runtime.h>

// LSTM B=8192, T=168, P=16, H=24, gates [i,f,g,o].
// Round-19: 6-wave single-chain blocks (2/CU) + lgkmcnt-only step barrier.
//  - Unified model fitting r9-r18: wave64 trans issue ~32 cyc/instr on a
//    pipe PARALLEL to VALU (not in VALUBusy). r18 = 672 (3 waves/SIMD x 7
//    trans x 32 = chip trans floor at 32 chains/CU, 7-trans cells) + 660
//    chain/barrier exposure = 1332 ✓. Only remaining lever: overlap the
//    660 with another block's trans issue via independent barriers.
//  - This round: r18 math/layout unchanged, but TWO 384-thr blocks/CU
//    (grid 512, NB=16, 6 waves = 1 chain). Same 3 waves/SIMD trans floor;
//    barrier population 12 -> 6; in-loop barrier = s_waitcnt lgkmcnt(0) +
//    s_barrier (no vmcnt/expcnt drain); cross-block slip now possible.
//  - 6-tile zero-waste map (r18): row rho of tile tau = gate rho&3 of unit
//    6*(rho>>2)+tau; B1 slot 8q+j = unit 6q+j (j<6). 1 cell/lane, u=6q+tau.
//  - Cell math identical to r12/r18 (fused denominator, 7 trans/cell).
//  - Decision rule: interval ~1330 unchanged => exposure is intrinsic =>
//    family floor reached (trans floor + recurrence latency).

#define T_STEPS 168
#define P_FEAT  16
#define TCH     84                 // t-chunk length (2 chunks)
#define NB      16                 // batches per block (one chain)
#define BPAD    24                 // f16 pad per batch (2-way banks)
#define BSTR    (TCH * 16 + BPAD)  // 1368 f16 per batch

typedef _Float16 half8 __attribute__((ext_vector_type(8)));
typedef _Float16 h2    __attribute__((ext_vector_type(2)));
typedef float    f32x4 __attribute__((ext_vector_type(4)));

__device__ __forceinline__ float rcp_fast(float x) {
#if __has_builtin(__builtin_amdgcn_rcpf)
    return __builtin_amdgcn_rcpf(x);
#else
    return 1.0f / x;
#endif
}
__device__ __forceinline__ float exp2_fast(float x) {
#if __has_builtin(__builtin_amdgcn_exp2f)
    return __builtin_amdgcn_exp2f(x);
#else
    return exp2f(x);
#endif
}
__device__ __forceinline__ float tanh_f(float x) {
    return 1.0f - 2.0f * rcp_fast(1.0f + exp2_fast(x * 2.88539008f));
}
__device__ __forceinline__ h2 pack2(float a, float b) {
    h2 r; r.x = (_Float16)a; r.y = (_Float16)b; return r;
}
// lgkmcnt(0) + s_barrier, WITHOUT the vmcnt(0)/expcnt drain __syncthreads
// adds. The T-loop has no VMEM ops; LDS ordering is exactly what's needed.
__device__ __forceinline__ void soft_barrier() {
    asm volatile("s_waitcnt lgkmcnt(0)\n\ts_barrier" ::: "memory");
}

__global__ __launch_bounds__(384, 3) void lstm_6w(
    const float* __restrict__ x,
    const float* __restrict__ W_ih,
    const float* __restrict__ W_hh,
    const float* __restrict__ b_ih,
    const float* __restrict__ b_hh,
    const float* __restrict__ W_lin,
    const float* __restrict__ b_lin,
    float* __restrict__ out)
{
    __shared__ __align__(16) _Float16 xs16[NB * BSTR];     // 43776 B (W-stage reused)
    __shared__ __align__(16) _Float16 hx[2][4][16][8];     //  2048 B ping-pong h
    __shared__ __align__(16) _Float16 zblk[16];            //    32 B zeros (B2 pad)
    __shared__ __align__(16) float    thbuf[16][25];       //  1600 B epilogue

    const int tid  = threadIdx.x;
    const int tau  = tid >> 6;        // wave 0..5: tile tau
    const int lane = tid & 63;
    const int n    = lane & 15;       // batch col (B/C) == row p supplied (A)
    const int q    = lane >> 4;       // k-chunk (A/B) == output row-quad (C)
    const int batch = blockIdx.x * NB + n;

    // ---- one-time: stage fused W (f32) into xs16 space ----
    float* wstage = reinterpret_cast<float*>(xs16);        // 96*40 f32
    for (int idx = tid; idx < 96 * 40; idx += 384) {
        const int j = idx / 40;
        const int k = idx - j * 40;
        wstage[idx] = (k < 24) ? W_hh[j * 24 + k] : W_ih[j * 16 + (k - 24)];
    }
    __syncthreads();

    // ---- A-fragments for this wave's tile (6-tile zero-waste map) ----
    // A row m=n: W row grow = gate (n&3) of unit 6*(n>>2)+tau.
    // A1 col j (slot 8q+j): W_hh[grow][6q+j] for j<6, pad j=6,7.
    // A2 col j: W_ih[grow][8q+j] for 8q+j<16 (q<2), else 0.
    half8 A1, A2;
    f32x4 biasf;
    {
        const int grow = (n & 3) * 24 + 6 * (n >> 2) + tau;
        #pragma unroll
        for (int j = 0; j < 8; j++) {
            A1[j] = (j < 6) ? (_Float16)wstage[grow * 40 + 6 * q + j] : (_Float16)0.0f;
            const int k = q * 8 + j;
            A2[j] = (k < 16) ? (_Float16)wstage[grow * 40 + 24 + k] : (_Float16)0.0f;
        }
        const int u = 6 * q + tau;    // this lane's unit (ALL lanes valid)
        #pragma unroll
        for (int r = 0; r < 4; r++)
            biasf[r] = b_ih[r * 24 + u] + b_hh[r * 24 + u];
    }
    // zero hx (both buffers; slots 6,7 stay 0 forever = K-pad) + zblk
    {
        unsigned* hz = reinterpret_cast<unsigned*>(&hx[0][0][0][0]);  // 512 dw
        hz[tid % 512] = 0u;                    // tids 0..383 cover 0..383
        if (tid < 128) hz[384 + tid] = 0u;     // cover 384..511
        if (tid < 8) reinterpret_cast<unsigned*>(zblk)[tid] = 0u;
    }
    __syncthreads();   // wstage dead; x staging reuses the space

    float c  = 0.0f;
    float hv = 0.0f;

    const float4* xsrc = reinterpret_cast<const float4*>(x)
                       + (size_t)(blockIdx.x * NB) * (T_STEPS * P_FEAT / 4);

    // B2 source: quads 0..1 read x halves, quads 2..3 the zero block
    const _Float16* xrowbase = (q < 2) ? &xs16[n * BSTR + q * 8] : zblk;
    const int xstep = (q < 2) ? 16 : 0;

    int bufp = 0;
    for (int ch = 0; ch < 2; ch++) {
        // stage NB x TCH x 16 f32 -> f16 (padded layout): 5376 float4, 14/thread
        for (int i = 0; i < 14; i++) {
            const int m   = tid + 384 * i;      // 0..5375
            const int b   = m / 336;            // 336 float4 per batch-chunk
            const int rem = m - b * 336;
            const float4 v = xsrc[(size_t)b * 672 + ch * 336 + rem];
            h2* dst = reinterpret_cast<h2*>(xs16) + b * (BSTR / 2) + rem * 2;
            dst[0] = pack2(v.x, v.y);
            dst[1] = pack2(v.z, v.w);
        }
        __syncthreads();

        // gx prologue for t=0 of this chunk
        f32x4 gx;
        {
            const half8 B2 = *reinterpret_cast<const half8*>(xrowbase);
            gx = __builtin_amdgcn_mfma_f32_16x16x32_f16(A2, B2, biasf, 0, 0, 0);
        }

        for (int t = 0; t < TCH; t++) {
            // B1: slot 8q+j = h of unit 6q+j, batch n (j written by wave j)
            const half8 B1 = *reinterpret_cast<const half8*>(&hx[bufp][q][n][0]);
            // prefetch next step's x fragment (last iter: dummy index 0)
            const int tn = (t + 1 < TCH) ? t + 1 : 0;
            const half8 B2n = *reinterpret_cast<const half8*>(xrowbase + tn * xstep);

            f32x4 g = __builtin_amdgcn_mfma_f32_16x16x32_f16(A1, B1, gx, 0, 0, 0);
            gx = __builtin_amdgcn_mfma_f32_16x16x32_f16(A2, B2n, biasf, 0, 0, 0);

            // fused-denominator activations: 7 trans for this lane's cell
            //   c' = [c(1+Y)(1+Z) + (1+X)(Z-1)] * rcp((1+X)(1+Y)(1+Z))
            //   h  = (W-1) * rcp((1+V)(1+W)),  W = e^{2*min(c',18)}
            {
                const float Y  = exp2_fast(g[0] * -1.44269504f);  // i
                const float X  = exp2_fast(g[1] * -1.44269504f);  // f
                const float Z  = exp2_fast(g[2] *  2.88539008f);  // g
                const float V  = exp2_fast(g[3] * -1.44269504f);  // o
                const float ax = 1.0f + X;
                const float ay = 1.0f + Y;
                const float az = 1.0f + Z;
                const float num = c * ay * az + ax * (Z - 1.0f);
                const float cn  = num * rcp_fast(ax * ay * az);
                c = cn;
                const float W  = exp2_fast(fminf(cn, 18.0f) * 2.88539008f);
                hv = (W - 1.0f) * rcp_fast((1.0f + V) * (1.0f + W));
            }

            // publish own unit to the other buffer (ALL lanes; slots 6,7 pad)
            hx[1 - bufp][q][n][tau] = (_Float16)hv;
            bufp ^= 1;
            soft_barrier();
        }
    }

    // ---- epilogue: out[b][u] = b_lin[u] + sum_k tanh(h[k]) * W_lin[u][k] ----
    thbuf[n][6 * q + tau] = tanh_f(hv);
    __syncthreads();

    {
        const int u = 6 * q + tau;
        const float* wl = &W_lin[u * 24];
        float acc = b_lin[u];
        #pragma unroll
        for (int k = 0; k < 24; k++) acc = fmaf(thbuf[n][k], wl[k], acc);
        out[(size_t)batch * 24 + u] = acc;
    }
}

extern "C" void kernel_launch(void* const* d_in, const int* in_sizes, int n_in,
                              void* d_out, int out_size, void* d_ws, size_t ws_size,
                              hipStream_t stream) {
    const float* x     = (const float*)d_in[0];
    const float* W_ih  = (const float*)d_in[1];
    const float* W_hh  = (const float*)d_in[2];
    const float* b_ih  = (const float*)d_in[3];
    const float* b_hh  = (const float*)d_in[4];
    const float* W_lin = (const float*)d_in[5];
    const float* b_lin = (const float*)d_in[6];
    float* out = (float*)d_out;

    const int B = in_sizes[0] / (T_STEPS * P_FEAT);   // 8192
    dim3 grid(B / NB), block(384);                    // 512 blocks x 6 waves
    lstm_6w<<<grid, block, 0, stream>>>(x, W_ih, W_hh, b_ih, b_hh, W_lin, b_lin, out);
}

// Round 12
// 190.143 us; speedup vs baseline: 1.0503x; 1.0503x over previous
//
#include <hip/hip_runtime.h>

// LSTM B=8192, T=168, P=16, H=24, gates [i,f,g,o].
// Round-20: r18 (93us best) + overhead elimination.
//  - r19 post-mortem: 6-wave blocks -> uneven SIMD fill (2+2+1+1), busiest
//    SIMD gates barrier: 1440. r18 12-wave balanced stands.
//  - Model re-fit (r10/r16/r18): trans issue nearly FREE (r10 -36 for -6
//    trans/wave; r16 +322 tracked VALU); interval = VALU-issue + chain +
//    convoy. Cell math is only ~150 cyc/SIMD of the 486 VALUBusy ->
//    2/3 of VALU is per-step OVERHEAD (dynamic bufp addressing, tn select,
//    loop control, packing). This round attacks that.
//  - Fix 1: T-loop unrolled x2 with STATIC ping-pong indices (84 steps =
//    even toggles -> chunk phases align), last two steps peeled -> no
//    per-iter select; LDS addresses loop-invariant.
//  - Fix 2: gate constants (-log2e for i,f,o; +2log2e for g) pre-folded
//    into staged W rows and bias -> exp2 args come straight from MFMA
//    (-4 VALU muls/cell).
//  - Fix 3: in-loop barrier = lgkmcnt(0)+s_barrier (no VMEM in loop).
//  - Layout/math otherwise identical to r18: 6-tile zero-waste map,
//    12 waves = 2 chains x 6 tiles, 256 blocks x 768 thr, LDS x-staging,
//    fused-denominator cell (7 trans).

#define T_STEPS 168
#define P_FEAT  16
#define TCH     84                 // t-chunk length (2 chunks)
#define NB      32                 // batches per block: 2 chains x 16
#define BPAD    24                 // f16 pad per batch (2-way banks)
#define BSTR    (TCH * 16 + BPAD)  // 1368 f16 per batch

typedef _Float16 half8 __attribute__((ext_vector_type(8)));
typedef _Float16 h2    __attribute__((ext_vector_type(2)));
typedef float    f32x4 __attribute__((ext_vector_type(4)));

__device__ __forceinline__ float rcp_fast(float x) {
#if __has_builtin(__builtin_amdgcn_rcpf)
    return __builtin_amdgcn_rcpf(x);
#else
    return 1.0f / x;
#endif
}
__device__ __forceinline__ float exp2_fast(float x) {
#if __has_builtin(__builtin_amdgcn_exp2f)
    return __builtin_amdgcn_exp2f(x);
#else
    return exp2f(x);
#endif
}
__device__ __forceinline__ float tanh_f(float x) {
    return 1.0f - 2.0f * rcp_fast(1.0f + exp2_fast(x * 2.88539008f));
}
__device__ __forceinline__ h2 pack2(float a, float b) {
    h2 r; r.x = (_Float16)a; r.y = (_Float16)b; return r;
}
// lgkmcnt(0)+s_barrier, no vmcnt/expcnt drain (T-loop has no VMEM ops).
__device__ __forceinline__ void soft_barrier() {
    asm volatile("s_waitcnt lgkmcnt(0)\n\ts_barrier" ::: "memory");
}

__global__ __launch_bounds__(768, 3) void lstm_6t(
    const float* __restrict__ x,
    const float* __restrict__ W_ih,
    const float* __restrict__ W_hh,
    const float* __restrict__ b_ih,
    const float* __restrict__ b_hh,
    const float* __restrict__ W_lin,
    const float* __restrict__ b_lin,
    float* __restrict__ out)
{
    __shared__ __align__(16) _Float16 xs16[NB * BSTR];      // 87552 B (W-stage reused)
    __shared__ __align__(16) _Float16 hx[2][2][4][16][8];   //  4096 B ping-pong h
    __shared__ __align__(16) _Float16 zblk[16];             //    32 B zeros (B2 pad)
    __shared__ __align__(16) float    thbuf[2][16][25];     //  3200 B epilogue

    const int tid  = threadIdx.x;
    const int w    = tid >> 6;        // wave 0..11
    const int lane = tid & 63;
    const int n    = lane & 15;       // batch col (B/C) == row p supplied (A)
    const int q    = lane >> 4;       // k-chunk (A/B) == output row-quad (C)
    const int cc   = (w >= 6);        // chain 0 / 1
    const int tau  = w - 6 * cc;      // tile 0..5 within chain
    const int batch = blockIdx.x * NB + 16 * cc + n;

    // ---- one-time: stage fused W (f32, PRE-SCALED per gate row) ----
    // row j (0..95): gate = j/24. i,f,o rows x -log2(e); g rows x +2*log2(e)
    // -> exp2 args come straight out of the MFMA accumulator.
    float* wstage = reinterpret_cast<float*>(xs16);         // 96*40 f32
    for (int idx = tid; idx < 96 * 40; idx += 768) {
        const int j = idx / 40;
        const int k = idx - j * 40;
        const int gate = j / 24;
        const float gsc = (gate == 2) ? 2.88539008f : -1.44269504f;
        wstage[idx] = gsc * ((k < 24) ? W_hh[j * 24 + k] : W_ih[j * 16 + (k - 24)]);
    }
    __syncthreads();

    // ---- A-fragments for this wave's tile (6-tile zero-waste map) ----
    // A row m=n: W row grow = gate (n&3) of unit 6*(n>>2)+tau.
    half8 A1, A2;
    f32x4 biasf;
    {
        const int grow = (n & 3) * 24 + 6 * (n >> 2) + tau;
        #pragma unroll
        for (int j = 0; j < 8; j++) {
            A1[j] = (j < 6) ? (_Float16)wstage[grow * 40 + 6 * q + j] : (_Float16)0.0f;
            const int k = q * 8 + j;
            A2[j] = (k < 16) ? (_Float16)wstage[grow * 40 + 24 + k] : (_Float16)0.0f;
        }
        const int u = 6 * q + tau;    // this lane's unit (ALL lanes valid)
        #pragma unroll
        for (int r = 0; r < 4; r++) {
            const float gsc = (r == 2) ? 2.88539008f : -1.44269504f;
            biasf[r] = gsc * (b_ih[r * 24 + u] + b_hh[r * 24 + u]);
        }
    }
    // zero hx (both buffers; slots 6,7 stay 0 forever = K-pad) + zblk
    {
        unsigned* hz = reinterpret_cast<unsigned*>(&hx[0][0][0][0][0]);  // 1024 dw
        if (tid < 512) { hz[tid] = 0u; hz[tid + 512] = 0u; }
        if (tid < 8) reinterpret_cast<unsigned*>(zblk)[tid] = 0u;
    }
    __syncthreads();   // wstage dead; x staging reuses the space

    float c  = 0.0f;
    float hv = 0.0f;

    const float4* xsrc = reinterpret_cast<const float4*>(x)
                       + (size_t)(blockIdx.x * NB) * (T_STEPS * P_FEAT / 4);

    // B2 source: quads 0..1 read x halves, quads 2..3 the zero block
    const _Float16* xrowbase = (q < 2) ? &xs16[(16 * cc + n) * BSTR + q * 8] : zblk;
    const int xstep = (q < 2) ? 16 : 0;

    // static ping-pong LDS addresses (loop-invariant)
    const _Float16* rd0 = &hx[0][cc][q][n][0];
    const _Float16* rd1 = &hx[1][cc][q][n][0];
    _Float16* wr0 = &hx[1][cc][q][n][tau];   // write target when reading buf0
    _Float16* wr1 = &hx[0][cc][q][n][tau];   // write target when reading buf1

    f32x4 gx;

    // one step: read B1 from rdb, prefetch x-frag, MFMA, act, write to wrb
    auto step = [&](const _Float16* rdb, _Float16* wrb, const _Float16* xfrag) {
        const half8 B1  = *reinterpret_cast<const half8*>(rdb);
        const half8 B2n = *reinterpret_cast<const half8*>(xfrag);
        f32x4 g = __builtin_amdgcn_mfma_f32_16x16x32_f16(A1, B1, gx, 0, 0, 0);
        gx = __builtin_amdgcn_mfma_f32_16x16x32_f16(A2, B2n, biasf, 0, 0, 0);
        // fused-denominator activations (args pre-scaled): 7 trans
        //   c' = [c(1+Y)(1+Z) + (1+X)(Z-1)] * rcp((1+X)(1+Y)(1+Z))
        //   h  = (W-1) * rcp((1+V)(1+W)),  W = e^{2*min(c',18)}
        {
            const float Y  = exp2_fast(g[0]);   // e^{-i_pre}
            const float X  = exp2_fast(g[1]);   // e^{-f_pre}
            const float Z  = exp2_fast(g[2]);   // e^{2 g_pre}
            const float V  = exp2_fast(g[3]);   // e^{-o_pre}
            const float ax = 1.0f + X;
            const float ay = 1.0f + Y;
            const float az = 1.0f + Z;
            const float num = c * ay * az + ax * (Z - 1.0f);
            const float cn  = num * rcp_fast(ax * ay * az);
            c = cn;
            const float W  = exp2_fast(fminf(cn, 18.0f) * 2.88539008f);
            hv = (W - 1.0f) * rcp_fast((1.0f + V) * (1.0f + W));
        }
        *wrb = (_Float16)hv;
        soft_barrier();
    };

    for (int ch = 0; ch < 2; ch++) {
        // stage NB x TCH x 16 f32 -> f16 (padded layout): 10752 float4, 14/thread
        for (int i = 0; i < 14; i++) {
            const int m   = tid + 768 * i;      // 0..10751
            const int b   = m / 336;            // 336 float4 per batch-chunk
            const int rem = m - b * 336;
            const float4 v = xsrc[(size_t)b * 672 + ch * 336 + rem];
            h2* dst = reinterpret_cast<h2*>(xs16) + b * (BSTR / 2) + rem * 2;
            dst[0] = pack2(v.x, v.y);
            dst[1] = pack2(v.z, v.w);
        }
        __syncthreads();

        // gx prologue for t=0 of this chunk
        gx = __builtin_amdgcn_mfma_f32_16x16x32_f16(
                 A2, *reinterpret_cast<const half8*>(xrowbase), biasf, 0, 0, 0);

        // t = 0..81 in 41 static double-steps (prefetch x(t+1) unconditional)
        for (int it = 0; it < 41; ++it) {
            const _Float16* xf = xrowbase + (2 * it + 1) * xstep;
            step(rd0, wr0, xf);              // even step, buf0 -> buf1
            step(rd1, wr1, xf + xstep);      // odd step,  buf1 -> buf0
        }
        // peeled: t=82 (prefetch x(83)), t=83 (dummy prefetch x(0))
        step(rd0, wr0, xrowbase + 83 * xstep);
        step(rd1, wr1, xrowbase);
        // 84 toggles = even -> next chunk starts at buf0 again
    }

    // ---- epilogue: out[b][u] = b_lin[u] + sum_k tanh(h[k]) * W_lin[u][k] ----
    thbuf[cc][n][6 * q + tau] = tanh_f(hv);
    __syncthreads();

    {
        const int u = 6 * q + tau;
        const float* wl = &W_lin[u * 24];
        float acc = b_lin[u];
        #pragma unroll
        for (int k = 0; k < 24; k++) acc = fmaf(thbuf[cc][n][k], wl[k], acc);
        out[(size_t)batch * 24 + u] = acc;
    }
}

extern "C" void kernel_launch(void* const* d_in, const int* in_sizes, int n_in,
                              void* d_out, int out_size, void* d_ws, size_t ws_size,
                              hipStream_t stream) {
    const float* x     = (const float*)d_in[0];
    const float* W_ih  = (const float*)d_in[1];
    const float* W_hh  = (const float*)d_in[2];
    const float* b_ih  = (const float*)d_in[3];
    const float* b_hh  = (const float*)d_in[4];
    const float* W_lin = (const float*)d_in[5];
    const float* b_lin = (const float*)d_in[6];
    float* out = (float*)d_out;

    const int B = in_sizes[0] / (T_STEPS * P_FEAT);   // 8192
    dim3 grid(B / NB), block(768);                    // 256 blocks x 12 waves
    lstm_6t<<<grid, block, 0, stream>>>(x, W_ih, W_hh, b_ih, b_hh, W_lin, b_lin, out);
}